// Round 2
// baseline (233.734 us; speedup 1.0000x reference)
//
#include <hip/hip_runtime.h>
#include <hip/hip_bf16.h>

// Problem constants
#define BATCH 256
#define CDIM  512
#define NPOS  49      // 7*7 attention positions
#define NPAD  64      // padded to 4 MFMA row-tiles
#define ASTRIDE 520   // fallback-kernel a_lds row stride

typedef __attribute__((ext_vector_type(8))) short bf16x8_t;  // MFMA A/B frag (4 VGPRs)
typedef __attribute__((ext_vector_type(4))) float f32x4_t;   // MFMA C/D frag

// ---------------------------------------------------------------------------
// ws layout (new path):
//   Wab    bf16 [512][512]   @ 0        (524288 B)
//   Whb    bf16 [512][512]   @ 524288
//   hb     bf16 [256][512]   @ 1048576  (262144 B)
//   pooled bf16 [256][64][512] @ 1310720 (16777216 B)  rows 49..63 = garbage (unused)
//   scores f32  [256][64]    @ 18087936 (65536 B)
// total 18153472 B
// ---------------------------------------------------------------------------
#define WS_NEED 18153472u

// ===========================================================================
// Kernel P: convert Wa, Wh, h to bf16; zero the score accumulator.
// grid 656 x 256  (65536 + 65536 + 32768 float4 tasks + 4096 zero-float4)
// ===========================================================================
__global__ __launch_bounds__(256) void prep(
    const float* __restrict__ Wa, const float* __restrict__ Wh,
    const float* __restrict__ h,
    __hip_bfloat16* __restrict__ Wab, __hip_bfloat16* __restrict__ Whb,
    __hip_bfloat16* __restrict__ hb, float* __restrict__ scores) {
    int gid = blockIdx.x * 256 + threadIdx.x;
    if (gid < 163840) {
        const float* src; __hip_bfloat16* dst; int idx;
        if (gid < 65536)       { src = Wa; dst = Wab; idx = gid; }
        else if (gid < 131072) { src = Wh; dst = Whb; idx = gid - 65536; }
        else                   { src = h;  dst = hb;  idx = gid - 131072; }
        float4 v = ((const float4*)src)[idx];
        dst[idx * 4 + 0] = __float2bfloat16(v.x);
        dst[idx * 4 + 1] = __float2bfloat16(v.y);
        dst[idx * 4 + 2] = __float2bfloat16(v.z);
        dst[idx * 4 + 3] = __float2bfloat16(v.w);
    } else {
        int idx = gid - 163840;                      // 0..4095
        ((float4*)scores)[idx] = (float4){0.f, 0.f, 0.f, 0.f};
    }
}

// ===========================================================================
// Kernel A: 2x2 avg-pool.  One block = (batch b, channel-group of 32).
// grid 4096 x 256.  LDS-staged coalesced float4 loads; each thread owns one
// (channel, pooled-row) pair and reads its 28 floats as 7 x ds_read_b128.
// Output pooled[b][n][c] bf16 (rows n>=49 untouched -> garbage, never read).
// ===========================================================================
__global__ __launch_bounds__(256, 6) void pool_kernel(
    const float* __restrict__ att_v, __hip_bfloat16* __restrict__ pooled) {
    __shared__ float4 lds[32 * 49];                  // 25088 B: 32 ch x 196 floats
    const int b  = blockIdx.x >> 4;
    const int cg = blockIdx.x & 15;
    const int t  = threadIdx.x;

    const float4* src = (const float4*)(att_v + ((size_t)b * CDIM + cg * 32) * 196);
    #pragma unroll
    for (int k = 0; k < 7; ++k) {                    // 7*256 = 1792 >= 1568
        int idx = t + k * 256;
        if (idx < 1568) lds[idx] = src[idx];
    }
    __syncthreads();

    const int i = t >> 5;                            // pooled row 0..7 (7 active)
    const int c = t & 31;                            // channel within group
    if (i < 7) {
        // rows 2i,2i+1 = 28 floats = 7 aligned float4 at base c*49 + 7i
        const float4* fp = &lds[c * 49 + 7 * i];
        float4 f0 = fp[0], f1 = fp[1], f2 = fp[2], f3 = fp[3];
        float4 f4 = fp[4], f5 = fp[5], f6 = fp[6];
        float p[7];
        p[0] = f0.x + f0.y + f3.z + f3.w;
        p[1] = f0.z + f0.w + f4.x + f4.y;
        p[2] = f1.x + f1.y + f4.z + f4.w;
        p[3] = f1.z + f1.w + f5.x + f5.y;
        p[4] = f2.x + f2.y + f5.z + f5.w;
        p[5] = f2.z + f2.w + f6.x + f6.y;
        p[6] = f3.x + f3.y + f6.z + f6.w;
        __hip_bfloat16* outp = pooled + (size_t)b * NPAD * CDIM + cg * 32 + c;
        #pragma unroll
        for (int j = 0; j < 7; ++j)
            outp[(size_t)(i * 7 + j) * CDIM] = __float2bfloat16(p[j] * 0.25f);
    }
}

// ===========================================================================
// Kernel B: per-batch GEMM tile 64(n) x 128(d), K=512 (a@Wa^T) + 512 (h@Wh^T,
// broadcast A) + fused tanh*Wd reduce -> atomicAdd into scores[b][n].
// grid 1024 (= 256 b x 4 col-tiles) x 256 (4 waves; wave w -> 32 cols).
// A/B frags read directly from global (L1/L2-hot) -> no LDS occupancy cap.
// ===========================================================================
__global__ __launch_bounds__(256, 4) void gemm_score(
    const __hip_bfloat16* __restrict__ pooled,
    const __hip_bfloat16* __restrict__ Wab,
    const __hip_bfloat16* __restrict__ Whb,
    const __hip_bfloat16* __restrict__ hb,
    const float* __restrict__ ba, const float* __restrict__ bh,
    const float* __restrict__ Wd, float* __restrict__ scores) {
    __shared__ float s_lds[NPAD];
    const int b    = blockIdx.x >> 2;
    const int jt   = blockIdx.x & 3;
    const int wave = threadIdx.x >> 6;
    const int lane = threadIdx.x & 63;
    const int q = lane >> 4;
    const int r = lane & 15;

    if (threadIdx.x < NPAD) s_lds[threadIdx.x] = 0.f;

    const int d0 = jt * 128 + wave * 32 + r;         // cols d0, d0+16
    const __hip_bfloat16* Ap = pooled + (size_t)b * NPAD * CDIM;
    const __hip_bfloat16* hp = hb + (size_t)b * CDIM;

    f32x4_t acc[4][2];
    #pragma unroll
    for (int rt = 0; rt < 4; ++rt)
        #pragma unroll
        for (int ct = 0; ct < 2; ++ct)
            acc[rt][ct] = (f32x4_t){0.f, 0.f, 0.f, 0.f};

    #pragma unroll 4
    for (int ks = 0; ks < 16; ++ks) {                // k = 0..511: a @ Wa^T
        const int k0 = ks * 32 + q * 8;
        bf16x8_t af[4], bf[2];
        #pragma unroll
        for (int rt = 0; rt < 4; ++rt)
            af[rt] = *(const bf16x8_t*)&Ap[(size_t)(rt * 16 + r) * CDIM + k0];
        #pragma unroll
        for (int ct = 0; ct < 2; ++ct)
            bf[ct] = *(const bf16x8_t*)&Wab[(size_t)(d0 + 16 * ct) * CDIM + k0];
        #pragma unroll
        for (int rt = 0; rt < 4; ++rt)
            #pragma unroll
            for (int ct = 0; ct < 2; ++ct)
                acc[rt][ct] = __builtin_amdgcn_mfma_f32_16x16x32_bf16(
                    af[rt], bf[ct], acc[rt][ct], 0, 0, 0);
    }
    #pragma unroll 4
    for (int ks = 0; ks < 16; ++ks) {                // k = 512..1023: h @ Wh^T
        const int k0 = ks * 32 + q * 8;
        bf16x8_t ah = *(const bf16x8_t*)&hp[k0];     // broadcast over rows
        bf16x8_t bf[2];
        #pragma unroll
        for (int ct = 0; ct < 2; ++ct)
            bf[ct] = *(const bf16x8_t*)&Whb[(size_t)(d0 + 16 * ct) * CDIM + k0];
        #pragma unroll
        for (int rt = 0; rt < 4; ++rt)
            #pragma unroll
            for (int ct = 0; ct < 2; ++ct)
                acc[rt][ct] = __builtin_amdgcn_mfma_f32_16x16x32_bf16(
                    ah, bf[ct], acc[rt][ct], 0, 0, 0);
    }

    // tanh + Wd-weighted reduction.  C/D layout: col=lane&15, row=q*4+reg.
    float part[4][4];
    #pragma unroll
    for (int rt = 0; rt < 4; ++rt)
        #pragma unroll
        for (int rg = 0; rg < 4; ++rg) part[rt][rg] = 0.f;
    #pragma unroll
    for (int ct = 0; ct < 2; ++ct) {
        const int d = d0 + 16 * ct;
        const float bias = ba[d] + bh[d];
        const float wd = Wd[d];
        #pragma unroll
        for (int rt = 0; rt < 4; ++rt)
            #pragma unroll
            for (int rg = 0; rg < 4; ++rg) {
                float x = acc[rt][ct][rg] + bias;
                float e = __expf(2.f * x);           // tanh = 1 - 2/(e^{2x}+1)
                part[rt][rg] += (1.f - 2.f / (e + 1.f)) * wd;
            }
    }
    #pragma unroll
    for (int m = 1; m < 16; m <<= 1)
        #pragma unroll
        for (int rt = 0; rt < 4; ++rt)
            #pragma unroll
            for (int rg = 0; rg < 4; ++rg)
                part[rt][rg] += __shfl_xor(part[rt][rg], m, 64);
    __syncthreads();                                 // s_lds zero-init visible
    if (r == 0) {
        #pragma unroll
        for (int rt = 0; rt < 4; ++rt)
            #pragma unroll
            for (int rg = 0; rg < 4; ++rg)
                atomicAdd(&s_lds[rt * 16 + q * 4 + rg], part[rt][rg]);
    }
    __syncthreads();
    if (threadIdx.x < NPAD)
        atomicAdd(&scores[b * NPAD + threadIdx.x], s_lds[threadIdx.x]);
}

// ===========================================================================
// Kernel C: softmax over 49 + weighted channel sum.
// grid 512 (= 256 b x 2 c-halves) x 256.  Each thread owns one channel.
// ===========================================================================
__global__ __launch_bounds__(256) void softmax_wsum(
    const float* __restrict__ scores, const __hip_bfloat16* __restrict__ pooled,
    float* __restrict__ out) {
    const int b  = blockIdx.x >> 1;
    const int ch = (blockIdx.x & 1) * 256 + threadIdx.x;
    const float* sp = scores + b * NPAD;
    float vmax = -3.0e38f;
    #pragma unroll
    for (int n = 0; n < NPOS; ++n) vmax = fmaxf(vmax, sp[n]);
    const __hip_bfloat16* Ap = pooled + (size_t)b * NPAD * CDIM + ch;
    float sum = 0.f, accv = 0.f;
    #pragma unroll
    for (int n = 0; n < NPOS; ++n) {
        float e = __expf(sp[n] - vmax);
        sum += e;
        accv += e * __bfloat162float(Ap[(size_t)n * CDIM]);
    }
    out[b * CDIM + ch] = accv / sum;
}

// ===========================================================================
// Fallback path (round-1 kernels, needs only 1 MB ws) — used if ws too small.
// ===========================================================================
__global__ void prep_convert(const float* __restrict__ Wa,
                             const float* __restrict__ Wh,
                             __hip_bfloat16* __restrict__ Wab,
                             __hip_bfloat16* __restrict__ Whb) {
    int gid = blockIdx.x * blockDim.x + threadIdx.x;
    const int quarter = (CDIM * CDIM) / 4;
    const float4* src; __hip_bfloat16* dst; int idx;
    if (gid < quarter) { src = (const float4*)Wa; dst = Wab; idx = gid; }
    else               { src = (const float4*)Wh; dst = Whb; idx = gid - quarter; }
    float4 v = src[idx];
    dst[idx * 4 + 0] = __float2bfloat16(v.x);
    dst[idx * 4 + 1] = __float2bfloat16(v.y);
    dst[idx * 4 + 2] = __float2bfloat16(v.z);
    dst[idx * 4 + 3] = __float2bfloat16(v.w);
}

__global__ __launch_bounds__(512, 2) void att_spp_main(
    const float* __restrict__ att_v, const float* __restrict__ h,
    const float* __restrict__ ba, const float* __restrict__ bh,
    const float* __restrict__ Wd,
    const __hip_bfloat16* __restrict__ Wab, const __hip_bfloat16* __restrict__ Whb,
    float* __restrict__ out) {
    __shared__ __hip_bfloat16 a_lds[NPAD * ASTRIDE];
    __shared__ __hip_bfloat16 h_lds[CDIM];
    __shared__ float babh_lds[CDIM];
    __shared__ float wd_lds[CDIM];
    __shared__ float scores_lds[NPAD];
    __shared__ float weights_lds[NPOS];
    const int b = blockIdx.x, t = threadIdx.x;
    h_lds[t]    = __float2bfloat16(h[b * CDIM + t]);
    babh_lds[t] = ba[t] + bh[t];
    wd_lds[t]   = Wd[t];
    if (t < NPAD) scores_lds[t] = 0.f;
    for (int idx = t; idx < (NPAD - NPOS) * ASTRIDE; idx += 512)
        a_lds[NPOS * ASTRIDE + idx] = __float2bfloat16(0.f);
    {
        const int jj = t & 7, g = t >> 3;
        const float2* att2 = (const float2*)(att_v + (size_t)b * CDIM * 196);
        if (jj < 7) {
            for (int ci = 0; ci < 8; ++ci) {
                const int c = g + (ci << 6), cbase = c * 98;
                #pragma unroll
                for (int i = 0; i < 7; ++i) {
                    float2 v0 = att2[cbase + i * 14 + jj];
                    float2 v1 = att2[cbase + i * 14 + 7 + jj];
                    a_lds[(i * 7 + jj) * ASTRIDE + c] =
                        __float2bfloat16((v0.x + v0.y + v1.x + v1.y) * 0.25f);
                }
            }
        }
    }
    __syncthreads();
    const int wave = t >> 6, lane = t & 63, q = lane >> 4, r = lane & 15;
    f32x4_t acc[4][4];
    #pragma unroll
    for (int rt = 0; rt < 4; ++rt)
        #pragma unroll
        for (int ct = 0; ct < 4; ++ct) acc[rt][ct] = (f32x4_t){0.f,0.f,0.f,0.f};
    const int dBase = wave * 64 + r;
    for (int ks = 0; ks < 16; ++ks) {
        const int k0 = ks * 32 + q * 8;
        bf16x8_t af[4], bf[4];
        #pragma unroll
        for (int rt = 0; rt < 4; ++rt)
            af[rt] = *(const bf16x8_t*)&a_lds[(rt * 16 + r) * ASTRIDE + k0];
        #pragma unroll
        for (int ct = 0; ct < 4; ++ct)
            bf[ct] = *(const bf16x8_t*)&Wab[(size_t)(dBase + ct * 16) * CDIM + k0];
        #pragma unroll
        for (int rt = 0; rt < 4; ++rt)
            #pragma unroll
            for (int ct = 0; ct < 4; ++ct)
                acc[rt][ct] = __builtin_amdgcn_mfma_f32_16x16x32_bf16(
                    af[rt], bf[ct], acc[rt][ct], 0, 0, 0);
    }
    for (int ks = 0; ks < 16; ++ks) {
        const int k0 = ks * 32 + q * 8;
        bf16x8_t af = *(const bf16x8_t*)&h_lds[k0];
        bf16x8_t bf[4];
        #pragma unroll
        for (int ct = 0; ct < 4; ++ct)
            bf[ct] = *(const bf16x8_t*)&Whb[(size_t)(dBase + ct * 16) * CDIM + k0];
        #pragma unroll
        for (int rt = 0; rt < 4; ++rt)
            #pragma unroll
            for (int ct = 0; ct < 4; ++ct)
                acc[rt][ct] = __builtin_amdgcn_mfma_f32_16x16x32_bf16(
                    af, bf[ct], acc[rt][ct], 0, 0, 0);
    }
    float part[4][4];
    #pragma unroll
    for (int rt = 0; rt < 4; ++rt)
        #pragma unroll
        for (int rg = 0; rg < 4; ++rg) part[rt][rg] = 0.f;
    #pragma unroll
    for (int ct = 0; ct < 4; ++ct) {
        const int d = dBase + ct * 16;
        const float bias = babh_lds[d], wd = wd_lds[d];
        #pragma unroll
        for (int rt = 0; rt < 4; ++rt)
            #pragma unroll
            for (int rg = 0; rg < 4; ++rg) {
                float x = acc[rt][ct][rg] + bias;
                float e = __expf(2.f * x);
                part[rt][rg] += (1.f - 2.f / (e + 1.f)) * wd;
            }
    }
    #pragma unroll
    for (int m = 1; m < 16; m <<= 1)
        #pragma unroll
        for (int rt = 0; rt < 4; ++rt)
            #pragma unroll
            for (int rg = 0; rg < 4; ++rg)
                part[rt][rg] += __shfl_xor(part[rt][rg], m, 64);
    if (r == 0) {
        #pragma unroll
        for (int rt = 0; rt < 4; ++rt)
            #pragma unroll
            for (int rg = 0; rg < 4; ++rg)
                atomicAdd(&scores_lds[rt * 16 + q * 4 + rg], part[rt][rg]);
    }
    __syncthreads();
    if (wave == 0) {
        float v = (lane < NPOS) ? scores_lds[lane] : -3.0e38f;
        float vmax = v;
        #pragma unroll
        for (int m = 1; m < 64; m <<= 1) vmax = fmaxf(vmax, __shfl_xor(vmax, m, 64));
        float e = (lane < NPOS) ? __expf(v - vmax) : 0.f;
        float s = e;
        #pragma unroll
        for (int m = 1; m < 64; m <<= 1) s += __shfl_xor(s, m, 64);
        if (lane < NPOS) weights_lds[lane] = e / s;
    }
    __syncthreads();
    float sum = 0.f;
    #pragma unroll
    for (int n = 0; n < NPOS; ++n)
        sum += __bfloat162float(a_lds[n * ASTRIDE + t]) * weights_lds[n];
    out[b * CDIM + t] = sum;
}

// ===========================================================================
extern "C" void kernel_launch(void* const* d_in, const int* in_sizes, int n_in,
                              void* d_out, int out_size, void* d_ws, size_t ws_size,
                              hipStream_t stream) {
    const float* att_v = (const float*)d_in[0];
    const float* h     = (const float*)d_in[1];
    const float* Wa    = (const float*)d_in[2];
    const float* ba    = (const float*)d_in[3];
    const float* Wh    = (const float*)d_in[4];
    const float* bh    = (const float*)d_in[5];
    const float* Wd    = (const float*)d_in[6];
    // d_in[7] = bd: dropped (softmax shift-invariant)

    if (ws_size >= WS_NEED) {
        char* ws = (char*)d_ws;
        __hip_bfloat16* Wab    = (__hip_bfloat16*)(ws);
        __hip_bfloat16* Whb    = (__hip_bfloat16*)(ws + 524288);
        __hip_bfloat16* hb     = (__hip_bfloat16*)(ws + 1048576);
        __hip_bfloat16* pooled = (__hip_bfloat16*)(ws + 1310720);
        float*          scores = (float*)(ws + 18087936);

        prep<<<656, 256, 0, stream>>>(Wa, Wh, h, Wab, Whb, hb, scores);
        pool_kernel<<<4096, 256, 0, stream>>>(att_v, pooled);
        gemm_score<<<1024, 256, 0, stream>>>(pooled, Wab, Whb, hb, ba, bh, Wd, scores);
        softmax_wsum<<<512, 256, 0, stream>>>(scores, pooled, (float*)d_out);
    } else {
        __hip_bfloat16* Wab = (__hip_bfloat16*)d_ws;
        __hip_bfloat16* Whb = Wab + (size_t)CDIM * CDIM;
        prep_convert<<<512, 256, 0, stream>>>(Wa, Wh, Wab, Whb);
        att_spp_main<<<BATCH, 512, 0, stream>>>(att_v, h, ba, bh, Wd, Wab, Whb,
                                                (float*)d_out);
    }
}

// Round 3
// 200.649 us; speedup vs baseline: 1.1649x; 1.1649x over previous
//
#include <hip/hip_runtime.h>
#include <hip/hip_bf16.h>

// Problem constants
#define BATCH 256
#define CDIM  512
#define NPOS  49        // 7*7 attention positions
#define MROWS 12544     // BATCH*NPOS, = 98*128 exactly
#define ASTRIDE 520     // fallback-kernel LDS stride

typedef __attribute__((ext_vector_type(8))) short bf16x8_t;  // MFMA A/B frag (4 VGPRs)
typedef __attribute__((ext_vector_type(4))) float f32x4_t;   // MFMA C/D frag

// ---------------------------------------------------------------------------
// ws layout (fast path):
//   Wab    bf16 [512][512]      @ 0         (524288)
//   Whb    bf16 [512][512]      @ 524288    (524288)
//   hb     bf16 [256][512]      @ 1048576   (262144)
//   pooled bf16 [12544][512]    @ 1310720   (12845056)   packed rows b*49+n
//   ahb    f32  [256][512]      @ 14155776  (524288)     h@Wh^T + ba + bh
//   scores f32  [12544]         @ 14680064  (50176)
// total 14730240 B
// ---------------------------------------------------------------------------
#define WS_NEED 14730240u

__device__ __forceinline__ void load_lds16(const void* g, void* l) {
    __builtin_amdgcn_global_load_lds(
        (const __attribute__((address_space(1))) void*)g,
        (__attribute__((address_space(3))) void*)l, 16, 0, 0);
}

// ===========================================================================
// prep: fp32->bf16 conversions + zero packed score accumulator.
// conv tasks: Wa 65536 + Wh 65536 + h 32768 float4 = 163840
// zero tasks: 12544/4 = 3136 float4   -> 166976 threads -> 653 blocks
// ===========================================================================
__global__ __launch_bounds__(256) void prep(
    const float* __restrict__ Wa, const float* __restrict__ Wh,
    const float* __restrict__ h,
    __hip_bfloat16* __restrict__ Wab, __hip_bfloat16* __restrict__ Whb,
    __hip_bfloat16* __restrict__ hb, float* __restrict__ scores) {
    int gid = blockIdx.x * 256 + threadIdx.x;
    if (gid >= 166976) return;
    if (gid < 163840) {
        const float* src; __hip_bfloat16* dst; int idx;
        if (gid < 65536)       { src = Wa; dst = Wab; idx = gid; }
        else if (gid < 131072) { src = Wh; dst = Whb; idx = gid - 65536; }
        else                   { src = h;  dst = hb;  idx = gid - 131072; }
        float4 v = ((const float4*)src)[idx];
        dst[idx * 4 + 0] = __float2bfloat16(v.x);
        dst[idx * 4 + 1] = __float2bfloat16(v.y);
        dst[idx * 4 + 2] = __float2bfloat16(v.z);
        dst[idx * 4 + 3] = __float2bfloat16(v.w);
    } else {
        int idx = gid - 163840;                      // 0..3135
        ((float4*)scores)[idx] = (float4){0.f, 0.f, 0.f, 0.f};
    }
}

// ===========================================================================
// pool: 2x2 avg-pool att_v[b] -> pooled[b*49+n][c] bf16 (packed).
// grid 4096 (= 256 b x 16 channel-groups of 32), 256 thr.
// Coalesced float4 global loads staged in LDS; each thread owns (c, pooled row i).
// ===========================================================================
__global__ __launch_bounds__(256, 6) void pool_kernel(
    const float* __restrict__ att_v, __hip_bfloat16* __restrict__ pooled) {
    __shared__ float4 lds[32 * 49];                  // 25088 B
    const int b  = blockIdx.x >> 4;
    const int cg = blockIdx.x & 15;
    const int t  = threadIdx.x;

    const float4* src = (const float4*)(att_v + ((size_t)b * CDIM + cg * 32) * 196);
    #pragma unroll
    for (int k = 0; k < 7; ++k) {
        int idx = t + k * 256;
        if (idx < 1568) lds[idx] = src[idx];
    }
    __syncthreads();

    const int i = t >> 5;                            // pooled row 0..7 (7 active)
    const int c = t & 31;
    if (i < 7) {
        const float4* fp = &lds[c * 49 + 7 * i];     // rows 2i,2i+1 = 7 float4
        float4 f0 = fp[0], f1 = fp[1], f2 = fp[2], f3 = fp[3];
        float4 f4 = fp[4], f5 = fp[5], f6 = fp[6];
        float p[7];
        p[0] = f0.x + f0.y + f3.z + f3.w;
        p[1] = f0.z + f0.w + f4.x + f4.y;
        p[2] = f1.x + f1.y + f4.z + f4.w;
        p[3] = f1.z + f1.w + f5.x + f5.y;
        p[4] = f2.x + f2.y + f5.z + f5.w;
        p[5] = f2.z + f2.w + f6.x + f6.y;
        p[6] = f3.x + f3.y + f6.z + f6.w;
        __hip_bfloat16* outp = pooled + ((size_t)b * NPOS + i * 7) * CDIM + cg * 32 + c;
        #pragma unroll
        for (int j = 0; j < 7; ++j)
            outp[(size_t)j * CDIM] = __float2bfloat16(p[j] * 0.25f);
    }
}

// ===========================================================================
// ah_gemm: ahb[b][d] = sum_c hb[b][c]*Whb[d][c] + ba[d] + bh[d].
// m97-style 128x128 tile, grid 8 (mt = bid&1, nt = bid>>1).  ~134 MFLOP.
// ===========================================================================
__global__ __launch_bounds__(256, 2) void ah_gemm(
    const __hip_bfloat16* __restrict__ A,   // hb [256][512]
    const __hip_bfloat16* __restrict__ Bw,  // Whb [512][512]
    const float* __restrict__ ba, const float* __restrict__ bh,
    float* __restrict__ ahb) {
    __shared__ __hip_bfloat16 aT[128 * 32];
    __shared__ __hip_bfloat16 bT[128 * 32];
    const int mt = blockIdx.x & 1;
    const int nt = blockIdx.x >> 1;
    const int t = threadIdx.x;
    const int wave = t >> 6, lane = t & 63;
    const int wm = wave & 1, wn = wave >> 1;
    const int q = lane >> 4, r = lane & 15;
    const int m0 = mt * 128, n0 = nt * 128;

    const __hip_bfloat16* Ag = A + (size_t)(m0 + wave * 16 + (lane >> 2)) * CDIM + (lane & 3) * 8;
    const __hip_bfloat16* Bg = Bw + (size_t)(n0 + wave * 16 + (lane >> 2)) * CDIM + (lane & 3) * 8;
    char* aD = (char*)aT + wave * 1024 + lane * 16;
    char* bD = (char*)bT + wave * 1024 + lane * 16;

    f32x4_t acc[4][4];
    #pragma unroll
    for (int rt = 0; rt < 4; ++rt)
        #pragma unroll
        for (int ct = 0; ct < 4; ++ct) acc[rt][ct] = (f32x4_t){0.f, 0.f, 0.f, 0.f};

    for (int ks = 0; ks < 16; ++ks) {
        const __hip_bfloat16* ag = Ag + ks * 32;
        const __hip_bfloat16* bg = Bg + ks * 32;
        load_lds16(ag, aD);
        load_lds16(ag + 64 * CDIM, aD + 4096);
        load_lds16(bg, bD);
        load_lds16(bg + 64 * CDIM, bD + 4096);
        __syncthreads();
        bf16x8_t af[4], bf[4];
        #pragma unroll
        for (int rt = 0; rt < 4; ++rt)
            af[rt] = *(const bf16x8_t*)&aT[(wm * 64 + rt * 16 + r) * 32 + q * 8];
        #pragma unroll
        for (int ct = 0; ct < 4; ++ct)
            bf[ct] = *(const bf16x8_t*)&bT[(wn * 64 + ct * 16 + r) * 32 + q * 8];
        #pragma unroll
        for (int rt = 0; rt < 4; ++rt)
            #pragma unroll
            for (int ct = 0; ct < 4; ++ct)
                acc[rt][ct] = __builtin_amdgcn_mfma_f32_16x16x32_bf16(
                    af[rt], bf[ct], acc[rt][ct], 0, 0, 0);
        __syncthreads();
    }
    // C/D: col = r (within 16), row = q*4+reg
    #pragma unroll
    for (int ct = 0; ct < 4; ++ct) {
        const int col = n0 + wn * 64 + ct * 16 + r;
        const float bias = ba[col] + bh[col];
        #pragma unroll
        for (int rt = 0; rt < 4; ++rt)
            #pragma unroll
            for (int rg = 0; rg < 4; ++rg) {
                const int row = m0 + wm * 64 + rt * 16 + q * 4 + rg;
                ahb[(size_t)row * CDIM + col] = acc[rt][ct][rg] + bias;
            }
    }
}

// ===========================================================================
// gemm_score2: D[row][d] = pooled[row][:] @ Wab[d][:]^T  (row = b*49+n),
// fused epilogue: scores[row] += sum_d tanh(D + ahb[b][d]) * Wd[d].
// M=12544, N=512, K=512.  grid 392 (mt = bid%98, nt = bid/98), 256 thr.
// m97 structure: global_load_lds 16B staging, ds_read_b128 frags, BK=32.
// ===========================================================================
__global__ __launch_bounds__(256, 2) void gemm_score2(
    const __hip_bfloat16* __restrict__ A,   // pooled [12544][512]
    const __hip_bfloat16* __restrict__ Bw,  // Wab [512][512]
    const float* __restrict__ ahb,          // [256][512]
    const float* __restrict__ Wd,           // [512]
    float* __restrict__ scores) {           // [12544]
    __shared__ __hip_bfloat16 aT[128 * 32];
    __shared__ __hip_bfloat16 bT[128 * 32];
    const int mt = blockIdx.x % 98;
    const int nt = blockIdx.x / 98;
    const int t = threadIdx.x;
    const int wave = t >> 6, lane = t & 63;
    const int wm = wave & 1, wn = wave >> 1;
    const int q = lane >> 4, r = lane & 15;
    const int m0 = mt * 128, n0 = nt * 128;

    const __hip_bfloat16* Ag = A + (size_t)(m0 + wave * 16 + (lane >> 2)) * CDIM + (lane & 3) * 8;
    const __hip_bfloat16* Bg = Bw + (size_t)(n0 + wave * 16 + (lane >> 2)) * CDIM + (lane & 3) * 8;
    char* aD = (char*)aT + wave * 1024 + lane * 16;
    char* bD = (char*)bT + wave * 1024 + lane * 16;

    f32x4_t acc[4][4];
    #pragma unroll
    for (int rt = 0; rt < 4; ++rt)
        #pragma unroll
        for (int ct = 0; ct < 4; ++ct) acc[rt][ct] = (f32x4_t){0.f, 0.f, 0.f, 0.f};

    for (int ks = 0; ks < 16; ++ks) {
        const __hip_bfloat16* ag = Ag + ks * 32;
        const __hip_bfloat16* bg = Bg + ks * 32;
        load_lds16(ag, aD);
        load_lds16(ag + 64 * CDIM, aD + 4096);
        load_lds16(bg, bD);
        load_lds16(bg + 64 * CDIM, bD + 4096);
        __syncthreads();
        bf16x8_t af[4], bf[4];
        #pragma unroll
        for (int rt = 0; rt < 4; ++rt)
            af[rt] = *(const bf16x8_t*)&aT[(wm * 64 + rt * 16 + r) * 32 + q * 8];
        #pragma unroll
        for (int ct = 0; ct < 4; ++ct)
            bf[ct] = *(const bf16x8_t*)&bT[(wn * 64 + ct * 16 + r) * 32 + q * 8];
        #pragma unroll
        for (int rt = 0; rt < 4; ++rt)
            #pragma unroll
            for (int ct = 0; ct < 4; ++ct)
                acc[rt][ct] = __builtin_amdgcn_mfma_f32_16x16x32_bf16(
                    af[rt], bf[ct], acc[rt][ct], 0, 0, 0);
        __syncthreads();
    }

    // Epilogue: rows m0+wm*64+rt*16+q*4+rg, cols n0+wn*64+ct*16+r.
    int bb[16];                                      // batch index per (rt,rg)
    #pragma unroll
    for (int rt = 0; rt < 4; ++rt)
        #pragma unroll
        for (int rg = 0; rg < 4; ++rg)
            bb[rt * 4 + rg] = (m0 + wm * 64 + rt * 16 + q * 4 + rg) / NPOS;

    float rsum[16];
    #pragma unroll
    for (int i = 0; i < 16; ++i) rsum[i] = 0.f;

    #pragma unroll
    for (int ct = 0; ct < 4; ++ct) {
        const int col = n0 + wn * 64 + ct * 16 + r;
        const float wd = Wd[col];
        #pragma unroll
        for (int rt = 0; rt < 4; ++rt)
            #pragma unroll
            for (int rg = 0; rg < 4; ++rg) {
                float x = acc[rt][ct][rg] + ahb[(size_t)bb[rt * 4 + rg] * CDIM + col];
                float e = __expf(2.f * x);           // tanh = 1 - 2/(e^{2x}+1)
                rsum[rt * 4 + rg] += (1.f - 2.f / (e + 1.f)) * wd;
            }
    }
    #pragma unroll
    for (int m = 1; m < 16; m <<= 1)
        #pragma unroll
        for (int i = 0; i < 16; ++i)
            rsum[i] += __shfl_xor(rsum[i], m, 64);
    if (r == 0) {
        #pragma unroll
        for (int rt = 0; rt < 4; ++rt)
            #pragma unroll
            for (int rg = 0; rg < 4; ++rg)
                atomicAdd(&scores[m0 + wm * 64 + rt * 16 + q * 4 + rg],
                          rsum[rt * 4 + rg]);
    }
}

// ===========================================================================
// softmax_wsum: softmax over 49 + weighted channel sum.
// grid 512 (= 256 b x 2 c-halves), thread owns one channel.
// ===========================================================================
__global__ __launch_bounds__(256) void softmax_wsum(
    const float* __restrict__ scores, const __hip_bfloat16* __restrict__ pooled,
    float* __restrict__ out) {
    const int b  = blockIdx.x >> 1;
    const int ch = (blockIdx.x & 1) * 256 + threadIdx.x;
    const float* sp = scores + b * NPOS;
    float vmax = -3.0e38f;
    #pragma unroll
    for (int n = 0; n < NPOS; ++n) vmax = fmaxf(vmax, sp[n]);
    const __hip_bfloat16* Ap = pooled + (size_t)b * NPOS * CDIM + ch;
    float sum = 0.f, accv = 0.f;
    #pragma unroll
    for (int n = 0; n < NPOS; ++n) {
        float e = __expf(sp[n] - vmax);
        sum += e;
        accv += e * __bfloat162float(Ap[(size_t)n * CDIM]);
    }
    out[b * CDIM + ch] = accv / sum;
}

// ===========================================================================
// Fallback path (round-1, 1 MB ws) — used only if ws too small.
// ===========================================================================
__global__ void prep_convert(const float* __restrict__ Wa,
                             const float* __restrict__ Wh,
                             __hip_bfloat16* __restrict__ Wab,
                             __hip_bfloat16* __restrict__ Whb) {
    int gid = blockIdx.x * blockDim.x + threadIdx.x;
    const int quarter = (CDIM * CDIM) / 4;
    const float4* src; __hip_bfloat16* dst; int idx;
    if (gid < quarter) { src = (const float4*)Wa; dst = Wab; idx = gid; }
    else               { src = (const float4*)Wh; dst = Whb; idx = gid - quarter; }
    float4 v = src[idx];
    dst[idx * 4 + 0] = __float2bfloat16(v.x);
    dst[idx * 4 + 1] = __float2bfloat16(v.y);
    dst[idx * 4 + 2] = __float2bfloat16(v.z);
    dst[idx * 4 + 3] = __float2bfloat16(v.w);
}

__global__ __launch_bounds__(512, 2) void att_spp_main(
    const float* __restrict__ att_v, const float* __restrict__ h,
    const float* __restrict__ ba, const float* __restrict__ bh,
    const float* __restrict__ Wd,
    const __hip_bfloat16* __restrict__ Wab, const __hip_bfloat16* __restrict__ Whb,
    float* __restrict__ out) {
    __shared__ __hip_bfloat16 a_lds[64 * ASTRIDE];
    __shared__ __hip_bfloat16 h_lds[CDIM];
    __shared__ float babh_lds[CDIM];
    __shared__ float wd_lds[CDIM];
    __shared__ float scores_lds[64];
    __shared__ float weights_lds[NPOS];
    const int b = blockIdx.x, t = threadIdx.x;
    h_lds[t]    = __float2bfloat16(h[b * CDIM + t]);
    babh_lds[t] = ba[t] + bh[t];
    wd_lds[t]   = Wd[t];
    if (t < 64) scores_lds[t] = 0.f;
    for (int idx = t; idx < (64 - NPOS) * ASTRIDE; idx += 512)
        a_lds[NPOS * ASTRIDE + idx] = __float2bfloat16(0.f);
    {
        const int jj = t & 7, g = t >> 3;
        const float2* att2 = (const float2*)(att_v + (size_t)b * CDIM * 196);
        if (jj < 7) {
            for (int ci = 0; ci < 8; ++ci) {
                const int c = g + (ci << 6), cbase = c * 98;
                #pragma unroll
                for (int i = 0; i < 7; ++i) {
                    float2 v0 = att2[cbase + i * 14 + jj];
                    float2 v1 = att2[cbase + i * 14 + 7 + jj];
                    a_lds[(i * 7 + jj) * ASTRIDE + c] =
                        __float2bfloat16((v0.x + v0.y + v1.x + v1.y) * 0.25f);
                }
            }
        }
    }
    __syncthreads();
    const int wave = t >> 6, lane = t & 63, q = lane >> 4, r = lane & 15;
    f32x4_t acc[4][4];
    #pragma unroll
    for (int rt = 0; rt < 4; ++rt)
        #pragma unroll
        for (int ct = 0; ct < 4; ++ct) acc[rt][ct] = (f32x4_t){0.f,0.f,0.f,0.f};
    const int dBase = wave * 64 + r;
    for (int ks = 0; ks < 16; ++ks) {
        const int k0 = ks * 32 + q * 8;
        bf16x8_t af[4], bf[4];
        #pragma unroll
        for (int rt = 0; rt < 4; ++rt)
            af[rt] = *(const bf16x8_t*)&a_lds[(rt * 16 + r) * ASTRIDE + k0];
        #pragma unroll
        for (int ct = 0; ct < 4; ++ct)
            bf[ct] = *(const bf16x8_t*)&Wab[(size_t)(dBase + ct * 16) * CDIM + k0];
        #pragma unroll
        for (int rt = 0; rt < 4; ++rt)
            #pragma unroll
            for (int ct = 0; ct < 4; ++ct)
                acc[rt][ct] = __builtin_amdgcn_mfma_f32_16x16x32_bf16(
                    af[rt], bf[ct], acc[rt][ct], 0, 0, 0);
    }
    for (int ks = 0; ks < 16; ++ks) {
        const int k0 = ks * 32 + q * 8;
        bf16x8_t af = *(const bf16x8_t*)&h_lds[k0];
        bf16x8_t bf[4];
        #pragma unroll
        for (int ct = 0; ct < 4; ++ct)
            bf[ct] = *(const bf16x8_t*)&Whb[(size_t)(dBase + ct * 16) * CDIM + k0];
        #pragma unroll
        for (int rt = 0; rt < 4; ++rt)
            #pragma unroll
            for (int ct = 0; ct < 4; ++ct)
                acc[rt][ct] = __builtin_amdgcn_mfma_f32_16x16x32_bf16(
                    af, bf[ct], acc[rt][ct], 0, 0, 0);
    }
    float part[4][4];
    #pragma unroll
    for (int rt = 0; rt < 4; ++rt)
        #pragma unroll
        for (int rg = 0; rg < 4; ++rg) part[rt][rg] = 0.f;
    #pragma unroll
    for (int ct = 0; ct < 4; ++ct) {
        const int d = dBase + ct * 16;
        const float bias = babh_lds[d], wd = wd_lds[d];
        #pragma unroll
        for (int rt = 0; rt < 4; ++rt)
            #pragma unroll
            for (int rg = 0; rg < 4; ++rg) {
                float x = acc[rt][ct][rg] + bias;
                float e = __expf(2.f * x);
                part[rt][rg] += (1.f - 2.f / (e + 1.f)) * wd;
            }
    }
    #pragma unroll
    for (int m = 1; m < 16; m <<= 1)
        #pragma unroll
        for (int rt = 0; rt < 4; ++rt)
            #pragma unroll
            for (int rg = 0; rg < 4; ++rg)
                part[rt][rg] += __shfl_xor(part[rt][rg], m, 64);
    if (r == 0) {
        #pragma unroll
        for (int rt = 0; rt < 4; ++rt)
            #pragma unroll
            for (int rg = 0; rg < 4; ++rg)
                atomicAdd(&scores_lds[rt * 16 + q * 4 + rg], part[rt][rg]);
    }
    __syncthreads();
    if (wave == 0) {
        float v = (lane < NPOS) ? scores_lds[lane] : -3.0e38f;
        float vmax = v;
        #pragma unroll
        for (int m = 1; m < 64; m <<= 1) vmax = fmaxf(vmax, __shfl_xor(vmax, m, 64));
        float e = (lane < NPOS) ? __expf(v - vmax) : 0.f;
        float s = e;
        #pragma unroll
        for (int m = 1; m < 64; m <<= 1) s += __shfl_xor(s, m, 64);
        if (lane < NPOS) weights_lds[lane] = e / s;
    }
    __syncthreads();
    float sum = 0.f;
    #pragma unroll
    for (int n = 0; n < NPOS; ++n)
        sum += __bfloat162float(a_lds[n * ASTRIDE + t]) * weights_lds[n];
    out[b * CDIM + t] = sum;
}

// ===========================================================================
extern "C" void kernel_launch(void* const* d_in, const int* in_sizes, int n_in,
                              void* d_out, int out_size, void* d_ws, size_t ws_size,
                              hipStream_t stream) {
    const float* att_v = (const float*)d_in[0];
    const float* h     = (const float*)d_in[1];
    const float* Wa    = (const float*)d_in[2];
    const float* ba    = (const float*)d_in[3];
    const float* Wh    = (const float*)d_in[4];
    const float* bh    = (const float*)d_in[5];
    const float* Wd    = (const float*)d_in[6];
    // d_in[7] = bd: dropped (softmax shift-invariant)

    if (ws_size >= WS_NEED) {
        char* ws = (char*)d_ws;
        __hip_bfloat16* Wab    = (__hip_bfloat16*)(ws);
        __hip_bfloat16* Whb    = (__hip_bfloat16*)(ws + 524288);
        __hip_bfloat16* hb     = (__hip_bfloat16*)(ws + 1048576);
        __hip_bfloat16* pooled = (__hip_bfloat16*)(ws + 1310720);
        float*          ahb    = (float*)(ws + 14155776);
        float*          scores = (float*)(ws + 14680064);

        prep<<<653, 256, 0, stream>>>(Wa, Wh, h, Wab, Whb, hb, scores);
        pool_kernel<<<4096, 256, 0, stream>>>(att_v, pooled);
        ah_gemm<<<8, 256, 0, stream>>>(hb, Whb, ba, bh, ahb);
        gemm_score2<<<392, 256, 0, stream>>>(pooled, Wab, ahb, Wd, scores);
        softmax_wsum<<<512, 256, 0, stream>>>(scores, pooled, (float*)d_out);
    } else {
        __hip_bfloat16* Wab = (__hip_bfloat16*)d_ws;
        __hip_bfloat16* Whb = Wab + (size_t)CDIM * CDIM;
        prep_convert<<<512, 256, 0, stream>>>(Wa, Wh, Wab, Whb);
        att_spp_main<<<BATCH, 512, 0, stream>>>(att_v, h, ba, bh, Wd, Wab, Whb,
                                                (float*)d_out);
    }
}

// Round 4
// 198.780 us; speedup vs baseline: 1.1758x; 1.0094x over previous
//
#include <hip/hip_runtime.h>
#include <hip/hip_bf16.h>

// Problem constants
#define BATCH 256
#define CDIM  512
#define NPOS  49        // 7*7 attention positions
#define MROWS 12544     // BATCH*NPOS
#define ASTRIDE 520     // fallback-kernel LDS stride

typedef __attribute__((ext_vector_type(8))) short bf16x8_t;  // MFMA A/B frag (4 VGPRs)
typedef __attribute__((ext_vector_type(4))) float f32x4_t;   // MFMA C/D frag

// ---------------------------------------------------------------------------
// ws layout (fast path):
//   Wab     bf16 [512][512]   @ 0         (524288)
//   Whb     bf16 [512][512]   @ 524288    (524288)
//   hb      bf16 [256][512]   @ 1048576   (262144)
//   pooled  bf16 [12544][512] @ 1310720   (12845056)   packed rows b*49+n
//   ahb     f32  [256][512]   @ 14155776  (524288)     h@Wh^T + ba + bh
//   scores8 f32  [8][12544]   @ 14680064  (401408)     per-(nt,wn) partials
// total 15081472 B
// ---------------------------------------------------------------------------
#define WS_NEED 15081472u

__device__ __forceinline__ void load_lds16(const void* g, void* l) {
    __builtin_amdgcn_global_load_lds(
        (const __attribute__((address_space(1))) void*)g,
        (__attribute__((address_space(3))) void*)l, 16, 0, 0);
}

// ===========================================================================
// prep: fp32->bf16 conversions only (no zeroing needed — scores are stores).
// tasks: Wa 65536 + Wh 65536 + h 32768 float4 = 163840 -> grid 640 x 256.
// ===========================================================================
__global__ __launch_bounds__(256) void prep(
    const float* __restrict__ Wa, const float* __restrict__ Wh,
    const float* __restrict__ h,
    __hip_bfloat16* __restrict__ Wab, __hip_bfloat16* __restrict__ Whb,
    __hip_bfloat16* __restrict__ hb) {
    int gid = blockIdx.x * 256 + threadIdx.x;
    const float* src; __hip_bfloat16* dst; int idx;
    if (gid < 65536)       { src = Wa; dst = Wab; idx = gid; }
    else if (gid < 131072) { src = Wh; dst = Whb; idx = gid - 65536; }
    else                   { src = h;  dst = hb;  idx = gid - 131072; }
    float4 v = ((const float4*)src)[idx];
    dst[idx * 4 + 0] = __float2bfloat16(v.x);
    dst[idx * 4 + 1] = __float2bfloat16(v.y);
    dst[idx * 4 + 2] = __float2bfloat16(v.z);
    dst[idx * 4 + 3] = __float2bfloat16(v.w);
}

// ===========================================================================
// pool: 2x2 avg-pool att_v[b] -> pooled[b*49+n][c] bf16 (packed).
// grid 4096 (= 256 b x 16 channel-groups of 32), 256 thr.
// ===========================================================================
__global__ __launch_bounds__(256, 6) void pool_kernel(
    const float* __restrict__ att_v, __hip_bfloat16* __restrict__ pooled) {
    __shared__ float4 lds[32 * 49];                  // 25088 B
    const int b  = blockIdx.x >> 4;
    const int cg = blockIdx.x & 15;
    const int t  = threadIdx.x;

    const float4* src = (const float4*)(att_v + ((size_t)b * CDIM + cg * 32) * 196);
    #pragma unroll
    for (int k = 0; k < 7; ++k) {
        int idx = t + k * 256;
        if (idx < 1568) lds[idx] = src[idx];
    }
    __syncthreads();

    const int i = t >> 5;                            // pooled row 0..7 (7 active)
    const int c = t & 31;
    if (i < 7) {
        const float4* fp = &lds[c * 49 + 7 * i];     // rows 2i,2i+1 = 7 float4
        float4 f0 = fp[0], f1 = fp[1], f2 = fp[2], f3 = fp[3];
        float4 f4 = fp[4], f5 = fp[5], f6 = fp[6];
        float p[7];
        p[0] = f0.x + f0.y + f3.z + f3.w;
        p[1] = f0.z + f0.w + f4.x + f4.y;
        p[2] = f1.x + f1.y + f4.z + f4.w;
        p[3] = f1.z + f1.w + f5.x + f5.y;
        p[4] = f2.x + f2.y + f5.z + f5.w;
        p[5] = f2.z + f2.w + f6.x + f6.y;
        p[6] = f3.x + f3.y + f6.z + f6.w;
        __hip_bfloat16* outp = pooled + ((size_t)b * NPOS + i * 7) * CDIM + cg * 32 + c;
        #pragma unroll
        for (int j = 0; j < 7; ++j)
            outp[(size_t)j * CDIM] = __float2bfloat16(p[j] * 0.25f);
    }
}

// ===========================================================================
// ah_gemm: ahb[b][d] = hb[b][:] @ Whb[d][:]^T + ba[d] + bh[d].
// 64x64 tiles: grid 32 (mt = bid&3 over 256 rows, nt = bid>>2 over 512 cols),
// 256 thr = 4 waves, each wave 32x32 (2x2 16x16 MFMA).
// ===========================================================================
__global__ __launch_bounds__(256, 4) void ah_gemm(
    const __hip_bfloat16* __restrict__ A,   // hb [256][512]
    const __hip_bfloat16* __restrict__ Bw,  // Whb [512][512]
    const float* __restrict__ ba, const float* __restrict__ bh,
    float* __restrict__ ahb) {
    __shared__ __hip_bfloat16 aT[64 * 32];
    __shared__ __hip_bfloat16 bT[64 * 32];
    const int mt = blockIdx.x & 3;
    const int nt = blockIdx.x >> 2;
    const int t = threadIdx.x;
    const int wave = t >> 6, lane = t & 63;
    const int wm = wave & 1, wn = wave >> 1;
    const int q = lane >> 4, r = lane & 15;
    const int m0 = mt * 64, n0 = nt * 64;

    const __hip_bfloat16* Ag = A + (size_t)(m0 + (t >> 2)) * CDIM + (t & 3) * 8;
    const __hip_bfloat16* Bg = Bw + (size_t)(n0 + (t >> 2)) * CDIM + (t & 3) * 8;
    char* aD = (char*)aT + t * 16;
    char* bD = (char*)bT + t * 16;

    f32x4_t acc[2][2];
    #pragma unroll
    for (int rt = 0; rt < 2; ++rt)
        #pragma unroll
        for (int ct = 0; ct < 2; ++ct) acc[rt][ct] = (f32x4_t){0.f, 0.f, 0.f, 0.f};

    for (int ks = 0; ks < 16; ++ks) {
        load_lds16(Ag + ks * 32, aD);
        load_lds16(Bg + ks * 32, bD);
        __syncthreads();
        bf16x8_t af[2], bf[2];
        #pragma unroll
        for (int rt = 0; rt < 2; ++rt)
            af[rt] = *(const bf16x8_t*)&aT[(wm * 32 + rt * 16 + r) * 32 + q * 8];
        #pragma unroll
        for (int ct = 0; ct < 2; ++ct)
            bf[ct] = *(const bf16x8_t*)&bT[(wn * 32 + ct * 16 + r) * 32 + q * 8];
        #pragma unroll
        for (int rt = 0; rt < 2; ++rt)
            #pragma unroll
            for (int ct = 0; ct < 2; ++ct)
                acc[rt][ct] = __builtin_amdgcn_mfma_f32_16x16x32_bf16(
                    af[rt], bf[ct], acc[rt][ct], 0, 0, 0);
        __syncthreads();
    }
    // C/D: col = r, row = q*4+reg
    #pragma unroll
    for (int ct = 0; ct < 2; ++ct) {
        const int col = n0 + wn * 32 + ct * 16 + r;
        const float bias = ba[col] + bh[col];
        #pragma unroll
        for (int rt = 0; rt < 2; ++rt)
            #pragma unroll
            for (int rg = 0; rg < 4; ++rg) {
                const int row = m0 + wm * 32 + rt * 16 + q * 4 + rg;
                ahb[(size_t)row * CDIM + col] = acc[rt][ct][rg] + bias;
            }
    }
}

// ===========================================================================
// gemm_score3: one block = (batch b, 128-col tile nt).  grid 256*4 = 1024
// = exactly 4 blocks/CU.  M-tile = 64 rows (49 valid + 15 pad), K=512.
// Epilogue: tanh(D + ahb[b][col])*Wd[col], reduce over cols, plain store to
// exclusive segment scores8[nt*2+wn][b*49+row]  (no atomics, no init).
// Pad rows may read garbage (in-bounds of ws) — guarded at store.
// ===========================================================================
__global__ __launch_bounds__(256, 4) void gemm_score3(
    const __hip_bfloat16* __restrict__ A,   // pooled [12544][512]
    const __hip_bfloat16* __restrict__ Bw,  // Wab [512][512]
    const float* __restrict__ ahb,          // [256][512]
    const float* __restrict__ Wd,           // [512]
    float* __restrict__ scores8) {          // [8][12544]
    __shared__ __hip_bfloat16 aT[64 * 32];   // 4 KB
    __shared__ __hip_bfloat16 bT[128 * 32];  // 8 KB
    const int b  = blockIdx.x >> 2;
    const int nt = blockIdx.x & 3;
    const int t = threadIdx.x;
    const int wave = t >> 6, lane = t & 63;
    const int wm = wave & 1, wn = wave >> 1;
    const int q = lane >> 4, r = lane & 15;
    const int m0 = b * NPOS;
    const int n0 = nt * 128;

    const __hip_bfloat16* Ag = A + (size_t)(m0 + (t >> 2)) * CDIM + (t & 3) * 8;
    const __hip_bfloat16* Bg = Bw + (size_t)(n0 + (t >> 2)) * CDIM + (t & 3) * 8;
    char* aD = (char*)aT + t * 16;
    char* bD = (char*)bT + t * 16;

    f32x4_t acc[2][4];                       // [row-tile 0..1][col-tile 0..3]
    #pragma unroll
    for (int rt = 0; rt < 2; ++rt)
        #pragma unroll
        for (int ct = 0; ct < 4; ++ct) acc[rt][ct] = (f32x4_t){0.f, 0.f, 0.f, 0.f};

    for (int ks = 0; ks < 16; ++ks) {
        load_lds16(Ag + ks * 32, aD);                    // A 64x32
        load_lds16(Bg + ks * 32, bD);                    // B rows 0..63
        load_lds16(Bg + (size_t)64 * CDIM + ks * 32, bD + 4096);  // B rows 64..127
        __syncthreads();
        bf16x8_t af[2], bf[4];
        #pragma unroll
        for (int rt = 0; rt < 2; ++rt)
            af[rt] = *(const bf16x8_t*)&aT[(wm * 32 + rt * 16 + r) * 32 + q * 8];
        #pragma unroll
        for (int ct = 0; ct < 4; ++ct)
            bf[ct] = *(const bf16x8_t*)&bT[(wn * 64 + ct * 16 + r) * 32 + q * 8];
        #pragma unroll
        for (int rt = 0; rt < 2; ++rt)
            #pragma unroll
            for (int ct = 0; ct < 4; ++ct)
                acc[rt][ct] = __builtin_amdgcn_mfma_f32_16x16x32_bf16(
                    af[rt], bf[ct], acc[rt][ct], 0, 0, 0);
        __syncthreads();
    }

    // Epilogue.  Rows: wm*32 + rt*16 + q*4 + rg;  cols: n0 + wn*64 + ct*16 + r.
    float rsum[2][4];
    #pragma unroll
    for (int rt = 0; rt < 2; ++rt)
        #pragma unroll
        for (int rg = 0; rg < 4; ++rg) rsum[rt][rg] = 0.f;

    const float* ahp = ahb + (size_t)b * CDIM;
    #pragma unroll
    for (int ct = 0; ct < 4; ++ct) {
        const int col = n0 + wn * 64 + ct * 16 + r;
        const float ah = ahp[col];
        const float wd = Wd[col];
        #pragma unroll
        for (int rt = 0; rt < 2; ++rt)
            #pragma unroll
            for (int rg = 0; rg < 4; ++rg) {
                float x = acc[rt][ct][rg] + ah;
                float e = __expf(2.f * x);               // tanh = 1 - 2/(e^{2x}+1)
                rsum[rt][rg] += (1.f - 2.f / (e + 1.f)) * wd;
            }
    }
    #pragma unroll
    for (int m = 1; m < 16; m <<= 1)
        #pragma unroll
        for (int rt = 0; rt < 2; ++rt)
            #pragma unroll
            for (int rg = 0; rg < 4; ++rg)
                rsum[rt][rg] += __shfl_xor(rsum[rt][rg], m, 64);
    if (r == 0) {
        float* seg = scores8 + (size_t)(nt * 2 + wn) * MROWS + m0;
        #pragma unroll
        for (int rt = 0; rt < 2; ++rt)
            #pragma unroll
            for (int rg = 0; rg < 4; ++rg) {
                const int row = wm * 32 + rt * 16 + q * 4 + rg;
                if (row < NPOS) seg[row] = rsum[rt][rg];
            }
    }
}

// ===========================================================================
// softmax_wsum: scores[n] = sum of 8 segments; softmax over 49; weighted sum.
// grid 512 (= 256 b x 2 c-halves), thread owns one channel.
// ===========================================================================
__global__ __launch_bounds__(256) void softmax_wsum(
    const float* __restrict__ scores8, const __hip_bfloat16* __restrict__ pooled,
    float* __restrict__ out) {
    __shared__ float s_lds[NPOS];
    const int b  = blockIdx.x >> 1;
    const int ch = (blockIdx.x & 1) * 256 + threadIdx.x;
    if (threadIdx.x < NPOS) {
        float s = 0.f;
        #pragma unroll
        for (int seg = 0; seg < 8; ++seg)
            s += scores8[(size_t)seg * MROWS + b * NPOS + threadIdx.x];
        s_lds[threadIdx.x] = s;
    }
    __syncthreads();
    float vmax = -3.0e38f;
    #pragma unroll
    for (int n = 0; n < NPOS; ++n) vmax = fmaxf(vmax, s_lds[n]);
    const __hip_bfloat16* Ap = pooled + (size_t)b * NPOS * CDIM + ch;
    float sum = 0.f, accv = 0.f;
    #pragma unroll
    for (int n = 0; n < NPOS; ++n) {
        float e = __expf(s_lds[n] - vmax);
        sum += e;
        accv += e * __bfloat162float(Ap[(size_t)n * CDIM]);
    }
    out[b * CDIM + ch] = accv / sum;
}

// ===========================================================================
// Fallback path (round-1, 1 MB ws) — used only if ws too small.
// ===========================================================================
__global__ void prep_convert(const float* __restrict__ Wa,
                             const float* __restrict__ Wh,
                             __hip_bfloat16* __restrict__ Wab,
                             __hip_bfloat16* __restrict__ Whb) {
    int gid = blockIdx.x * blockDim.x + threadIdx.x;
    const int quarter = (CDIM * CDIM) / 4;
    const float4* src; __hip_bfloat16* dst; int idx;
    if (gid < quarter) { src = (const float4*)Wa; dst = Wab; idx = gid; }
    else               { src = (const float4*)Wh; dst = Whb; idx = gid - quarter; }
    float4 v = src[idx];
    dst[idx * 4 + 0] = __float2bfloat16(v.x);
    dst[idx * 4 + 1] = __float2bfloat16(v.y);
    dst[idx * 4 + 2] = __float2bfloat16(v.z);
    dst[idx * 4 + 3] = __float2bfloat16(v.w);
}

__global__ __launch_bounds__(512, 2) void att_spp_main(
    const float* __restrict__ att_v, const float* __restrict__ h,
    const float* __restrict__ ba, const float* __restrict__ bh,
    const float* __restrict__ Wd,
    const __hip_bfloat16* __restrict__ Wab, const __hip_bfloat16* __restrict__ Whb,
    float* __restrict__ out) {
    __shared__ __hip_bfloat16 a_lds[64 * ASTRIDE];
    __shared__ __hip_bfloat16 h_lds[CDIM];
    __shared__ float babh_lds[CDIM];
    __shared__ float wd_lds[CDIM];
    __shared__ float scores_lds[64];
    __shared__ float weights_lds[NPOS];
    const int b = blockIdx.x, t = threadIdx.x;
    h_lds[t]    = __float2bfloat16(h[b * CDIM + t]);
    babh_lds[t] = ba[t] + bh[t];
    wd_lds[t]   = Wd[t];
    if (t < 64) scores_lds[t] = 0.f;
    for (int idx = t; idx < (64 - NPOS) * ASTRIDE; idx += 512)
        a_lds[NPOS * ASTRIDE + idx] = __float2bfloat16(0.f);
    {
        const int jj = t & 7, g = t >> 3;
        const float2* att2 = (const float2*)(att_v + (size_t)b * CDIM * 196);
        if (jj < 7) {
            for (int ci = 0; ci < 8; ++ci) {
                const int c = g + (ci << 6), cbase = c * 98;
                #pragma unroll
                for (int i = 0; i < 7; ++i) {
                    float2 v0 = att2[cbase + i * 14 + jj];
                    float2 v1 = att2[cbase + i * 14 + 7 + jj];
                    a_lds[(i * 7 + jj) * ASTRIDE + c] =
                        __float2bfloat16((v0.x + v0.y + v1.x + v1.y) * 0.25f);
                }
            }
        }
    }
    __syncthreads();
    const int wave = t >> 6, lane = t & 63, q = lane >> 4, r = lane & 15;
    f32x4_t acc[4][4];
    #pragma unroll
    for (int rt = 0; rt < 4; ++rt)
        #pragma unroll
        for (int ct = 0; ct < 4; ++ct) acc[rt][ct] = (f32x4_t){0.f,0.f,0.f,0.f};
    const int dBase = wave * 64 + r;
    for (int ks = 0; ks < 16; ++ks) {
        const int k0 = ks * 32 + q * 8;
        bf16x8_t af[4], bf[4];
        #pragma unroll
        for (int rt = 0; rt < 4; ++rt)
            af[rt] = *(const bf16x8_t*)&a_lds[(rt * 16 + r) * ASTRIDE + k0];
        #pragma unroll
        for (int ct = 0; ct < 4; ++ct)
            bf[ct] = *(const bf16x8_t*)&Wab[(size_t)(dBase + ct * 16) * CDIM + k0];
        #pragma unroll
        for (int rt = 0; rt < 4; ++rt)
            #pragma unroll
            for (int ct = 0; ct < 4; ++ct)
                acc[rt][ct] = __builtin_amdgcn_mfma_f32_16x16x32_bf16(
                    af[rt], bf[ct], acc[rt][ct], 0, 0, 0);
    }
    for (int ks = 0; ks < 16; ++ks) {
        const int k0 = ks * 32 + q * 8;
        bf16x8_t af = *(const bf16x8_t*)&h_lds[k0];
        bf16x8_t bf[4];
        #pragma unroll
        for (int ct = 0; ct < 4; ++ct)
            bf[ct] = *(const bf16x8_t*)&Whb[(size_t)(dBase + ct * 16) * CDIM + k0];
        #pragma unroll
        for (int rt = 0; rt < 4; ++rt)
            #pragma unroll
            for (int ct = 0; ct < 4; ++ct)
                acc[rt][ct] = __builtin_amdgcn_mfma_f32_16x16x32_bf16(
                    af, bf[ct], acc[rt][ct], 0, 0, 0);
    }
    float part[4][4];
    #pragma unroll
    for (int rt = 0; rt < 4; ++rt)
        #pragma unroll
        for (int rg = 0; rg < 4; ++rg) part[rt][rg] = 0.f;
    #pragma unroll
    for (int ct = 0; ct < 4; ++ct) {
        const int d = dBase + ct * 16;
        const float bias = babh_lds[d], wd = wd_lds[d];
        #pragma unroll
        for (int rt = 0; rt < 4; ++rt)
            #pragma unroll
            for (int rg = 0; rg < 4; ++rg) {
                float x = acc[rt][ct][rg] + bias;
                float e = __expf(2.f * x);
                part[rt][rg] += (1.f - 2.f / (e + 1.f)) * wd;
            }
    }
    #pragma unroll
    for (int m = 1; m < 16; m <<= 1)
        #pragma unroll
        for (int rt = 0; rt < 4; ++rt)
            #pragma unroll
            for (int rg = 0; rg < 4; ++rg)
                part[rt][rg] += __shfl_xor(part[rt][rg], m, 64);
    if (r == 0) {
        #pragma unroll
        for (int rt = 0; rt < 4; ++rt)
            #pragma unroll
            for (int rg = 0; rg < 4; ++rg)
                atomicAdd(&scores_lds[rt * 16 + q * 4 + rg], part[rt][rg]);
    }
    __syncthreads();
    if (wave == 0) {
        float v = (lane < NPOS) ? scores_lds[lane] : -3.0e38f;
        float vmax = v;
        #pragma unroll
        for (int m = 1; m < 64; m <<= 1) vmax = fmaxf(vmax, __shfl_xor(vmax, m, 64));
        float e = (lane < NPOS) ? __expf(v - vmax) : 0.f;
        float s = e;
        #pragma unroll
        for (int m = 1; m < 64; m <<= 1) s += __shfl_xor(s, m, 64);
        if (lane < NPOS) weights_lds[lane] = e / s;
    }
    __syncthreads();
    float sum = 0.f;
    #pragma unroll
    for (int n = 0; n < NPOS; ++n)
        sum += __bfloat162float(a_lds[n * ASTRIDE + t]) * weights_lds[n];
    out[b * CDIM + t] = sum;
}

// ===========================================================================
extern "C" void kernel_launch(void* const* d_in, const int* in_sizes, int n_in,
                              void* d_out, int out_size, void* d_ws, size_t ws_size,
                              hipStream_t stream) {
    const float* att_v = (const float*)d_in[0];
    const float* h     = (const float*)d_in[1];
    const float* Wa    = (const float*)d_in[2];
    const float* ba    = (const float*)d_in[3];
    const float* Wh    = (const float*)d_in[4];
    const float* bh    = (const float*)d_in[5];
    const float* Wd    = (const float*)d_in[6];
    // d_in[7] = bd: dropped (softmax shift-invariant)

    if (ws_size >= WS_NEED) {
        char* ws = (char*)d_ws;
        __hip_bfloat16* Wab     = (__hip_bfloat16*)(ws);
        __hip_bfloat16* Whb     = (__hip_bfloat16*)(ws + 524288);
        __hip_bfloat16* hb      = (__hip_bfloat16*)(ws + 1048576);
        __hip_bfloat16* pooled  = (__hip_bfloat16*)(ws + 1310720);
        float*          ahb     = (float*)(ws + 14155776);
        float*          scores8 = (float*)(ws + 14680064);

        prep<<<640, 256, 0, stream>>>(Wa, Wh, h, Wab, Whb, hb);
        pool_kernel<<<4096, 256, 0, stream>>>(att_v, pooled);
        ah_gemm<<<32, 256, 0, stream>>>(hb, Whb, ba, bh, ahb);
        gemm_score3<<<1024, 256, 0, stream>>>(pooled, Wab, ahb, Wd, scores8);
        softmax_wsum<<<512, 256, 0, stream>>>(scores8, pooled, (float*)d_out);
    } else {
        __hip_bfloat16* Wab = (__hip_bfloat16*)d_ws;
        __hip_bfloat16* Whb = Wab + (size_t)CDIM * CDIM;
        prep_convert<<<512, 256, 0, stream>>>(Wa, Wh, Wab, Whb);
        att_spp_main<<<BATCH, 512, 0, stream>>>(att_v, h, ba, bh, Wd, Wab, Whb,
                                                (float*)d_out);
    }
}